// Round 15
// baseline (125.342 us; speedup 1.0000x reference)
//
#include <hip/hip_runtime.h>
#include <hip/hip_bf16.h>
#include <math.h>

#define IN_F 128
#define OUT_F 64
#define BKT_SH 8          // 256 nodes per bucket
#define BKT_MASK 255
#define CHUNK 4096        // edges per partition block (196 blocks at E=800k)
#define MAXTB 800         // max total buckets (2 * ceil(n/256)); n<=102k
#define IDX_BITS 24       // packed tmp: (local<<24)|idx ; needs n,E < 2^24
#define IDX_MASK ((1u << IDX_BITS) - 1u)
#define PAD 16            // bcnt/gfill padding: one counter per 64B line

typedef __attribute__((ext_vector_type(8))) short bf16x8;
typedef __attribute__((ext_vector_type(4))) float f32x4;

__device__ inline short f2bf(float x) {
    __hip_bfloat16 b = __float2bfloat16(x);
    return *reinterpret_cast<short*>(&b);
}
__device__ inline float bflo(unsigned u) { return __uint_as_float(u << 16); }
__device__ inline float bfhi(unsigned u) { return __uint_as_float(u & 0xffff0000u); }

// ===================== fused: MFMA dual GEMM + bucket count =====================
__global__ __launch_bounds__(256) void k_fused(const float* __restrict__ h,
                                               const float* __restrict__ Wg,
                                               const float* __restrict__ Wc,
                                               const float* __restrict__ attn_l,
                                               const float* __restrict__ attn_r,
                                               __hip_bfloat16* __restrict__ feat,
                                               __hip_bfloat16* __restrict__ support,
                                               float* __restrict__ el,
                                               float* __restrict__ er, int n, int G1,
                                               const int* __restrict__ dst0,
                                               const int* __restrict__ row2,
                                               int* __restrict__ bcnt,
                                               int* __restrict__ chunkhist,
                                               int NB, int E_) {
    __shared__ short Wl[16][128][8];   // 32 KB
    __shared__ int hist[MAXTB];        // 3.2 KB

    if ((int)blockIdx.x >= G1) {
        // ---------- count part ----------
        int TB = 2 * NB;
        int t = threadIdx.x;
        int chunk = (int)blockIdx.x - G1;
        for (int i = t; i < TB; i += 256) hist[i] = 0;
        __syncthreads();
        int e0 = chunk * CHUNK;
        for (int i = t; i < CHUNK; i += 256) {
            int e = e0 + i;
            if (e < E_) {
                atomicAdd(&hist[dst0[e] >> BKT_SH], 1);
                atomicAdd(&hist[NB + (row2[e] >> BKT_SH)], 1);
            }
        }
        __syncthreads();
        int* hrow = chunkhist + (size_t)chunk * TB;
        for (int b = t; b < TB; b += 256) {
            int c = hist[b];
            hrow[b] = c;
            if (c) atomicAdd(&bcnt[b * PAD], c);   // padded: 1 counter / line
        }
        return;
    }

    // ---------- GEMM part ----------
    for (int i = threadIdx.x; i < 128 * 32; i += 256) {
        int k = i >> 5;
        int c4 = (i & 31) << 2;
        float4 v4 = (c4 < 64) ? *(const float4*)(Wg + k * 64 + c4)
                              : *(const float4*)(Wc + k * 64 + (c4 - 64));
        short* dst = &Wl[k >> 3][c4][k & 7];
        dst[0]  = f2bf(v4.x);
        dst[8]  = f2bf(v4.y);
        dst[16] = f2bf(v4.z);
        dst[24] = f2bf(v4.w);
    }
    __syncthreads();

    int lane = threadIdx.x & 63;
    int wv = threadIdx.x >> 6;
    int li = lane & 15, lg = lane >> 4;
    int row0 = blockIdx.x * 64 + wv * 16;

    f32x4 acc[8];
#pragma unroll
    for (int ct = 0; ct < 8; ++ct) acc[ct] = (f32x4){0.f, 0.f, 0.f, 0.f};

    int ar = row0 + li;
    if (ar >= n) ar = n - 1;
    const float* hrow = h + (size_t)ar * IN_F + lg * 8;
#pragma unroll
    for (int q = 0; q < 4; ++q) {
        float4 a0 = *(const float4*)(hrow + q * 32);
        float4 a1 = *(const float4*)(hrow + q * 32 + 4);
        bf16x8 af;
        af[0] = f2bf(a0.x); af[1] = f2bf(a0.y); af[2] = f2bf(a0.z); af[3] = f2bf(a0.w);
        af[4] = f2bf(a1.x); af[5] = f2bf(a1.y); af[6] = f2bf(a1.z); af[7] = f2bf(a1.w);
        int kg = q * 4 + lg;
#pragma unroll
        for (int ct = 0; ct < 8; ++ct) {
            bf16x8 bfr = *(const bf16x8*)&Wl[kg][ct * 16 + li][0];
            acc[ct] = __builtin_amdgcn_mfma_f32_16x16x32_bf16(af, bfr, acc[ct], 0, 0, 0);
        }
    }

    float alv[4], arv[4];
#pragma unroll
    for (int ct = 0; ct < 4; ++ct) {
        alv[ct] = attn_l[ct * 16 + li];
        arv[ct] = attn_r[ct * 16 + li];
    }
#pragma unroll
    for (int r = 0; r < 4; ++r) {
        int row = row0 + lg * 4 + r;
        float pl = 0.f, pr = 0.f;
#pragma unroll
        for (int ct = 0; ct < 4; ++ct) {
            pl += acc[ct][r] * alv[ct];
            pr += acc[ct][r] * arv[ct];
        }
#pragma unroll
        for (int m = 8; m; m >>= 1) {
            pl += __shfl_xor(pl, m);
            pr += __shfl_xor(pr, m);
        }
        if (li == 0 && row < n) { el[row] = pl; er[row] = pr; }
    }

#pragma unroll
    for (int r = 0; r < 4; ++r) {
        int row = row0 + lg * 4 + r;
        if (row >= n) continue;
#pragma unroll
        for (int ct = 0; ct < 4; ++ct)
            feat[(size_t)row * OUT_F + ct * 16 + li] = __float2bfloat16(acc[ct][r]);
#pragma unroll
        for (int ct = 4; ct < 8; ++ct)
            support[(size_t)row * OUT_F + (ct - 4) * 16 + li] = __float2bfloat16(acc[ct][r]);
    }
}

// ===================== partition: per-block scan of bcnt + scatter ============
__global__ __launch_bounds__(256) void k_part(const int* __restrict__ src0,
                                              const int* __restrict__ dst0,
                                              const int* __restrict__ row2,
                                              const int* __restrict__ col2,
                                              const float* __restrict__ adj_val,
                                              const float* __restrict__ el,
                                              const float* __restrict__ er,
                                              const int* __restrict__ bcnt,
                                              const int* __restrict__ chunkhist,
                                              int* __restrict__ gfill,
                                              int* __restrict__ boffs,
                                              int* __restrict__ offs, int tot,
                                              int2* __restrict__ tmp,
                                              int NB, int E_, int grand) {
    __shared__ int bo[MAXTB + 1];      // local boffs
    __shared__ int hist[MAXTB];
    __shared__ int rbase[MAXTB];
    __shared__ int sh[256];
    int TB = 2 * NB;
    int t = threadIdx.x;

    // ---- block-local exclusive scan of bcnt ----
    {
        int base = t * 4;
        int v[4];
        int sum = 0;
#pragma unroll
        for (int i = 0; i < 4; ++i) {
            int idx = base + i;
            v[i] = (idx < TB) ? bcnt[idx * PAD] : 0;
            sum += v[i];
        }
        sh[t] = sum;
        __syncthreads();
        for (int off = 1; off < 256; off <<= 1) {
            int x = (t >= off) ? sh[t - off] : 0;
            __syncthreads();
            sh[t] += x;
            __syncthreads();
        }
        int run = sh[t] - sum;
#pragma unroll
        for (int i = 0; i < 4; ++i) {
            int idx = base + i;
            if (idx < TB) bo[idx] = run;
            run += v[i];
        }
        if (t == 0) bo[TB] = grand;
    }
    __syncthreads();

    if (blockIdx.x == 0) {
        for (int b = t; b <= TB; b += 256) boffs[b] = bo[b];
        if (t == 0) offs[tot] = grand;
    }

    const int* hrow = chunkhist + (size_t)blockIdx.x * TB;
    for (int b = t; b < TB; b += 256) {
        int c = hrow[b];
        int bb = 0;
        if (c) bb = bo[b] + atomicAdd(&gfill[b * PAD], c);
        rbase[b] = bb;
        hist[b] = 0;   // local fill counters
    }
    __syncthreads();
    int e0 = blockIdx.x * CHUNK;
    for (int i = t; i < CHUNK; i += 256) {
        int e = e0 + i;
        if (e < E_) {
            int s = src0[e];
            int d = dst0[e];
            int b = d >> BKT_SH;
            int p = atomicAdd(&hist[b], 1);
            float w = el[s] + er[d];
            w = w > 0.f ? w : 0.2f * w;
            w = __expf(w);                       // no-max softmax
            tmp[(size_t)rbase[b] + p] =
                make_int2((int)(((unsigned)(d & BKT_MASK) << IDX_BITS) | (unsigned)s),
                          __float_as_int(w));
            int r = row2[e];
            int b2 = NB + (r >> BKT_SH);
            int p2 = atomicAdd(&hist[b2], 1);
            tmp[(size_t)rbase[b2] + p2] =
                make_int2((int)(((unsigned)(r & BKT_MASK) << IDX_BITS) | (unsigned)col2[e]),
                          __float_as_int(adj_val[e]));
        }
    }
}

// ===================== build fine CSR (gather-free permute) ==========
// Packs ew entries to 4 bytes: (bf16(w) << 16) | node_idx (n < 65536).
__global__ __launch_bounds__(256) void k_bbuild(const int2* __restrict__ tmp,
                                                const int* __restrict__ boffs,
                                                int* __restrict__ offs,
                                                unsigned* __restrict__ ew, int NB, int n) {
    __shared__ int hcnt[256], hoff[256], hfill[256], sh[256];
    int b = blockIdx.x;
    int t = threadIdx.x;
    int base = boffs[b];
    int cnt = boffs[b + 1] - base;
    bool isGat = b < NB;
    int nodeBase = (isGat ? b : b - NB) << BKT_SH;
    int offsBase = (isGat ? 0 : n) + nodeBase;

    hcnt[t] = 0;
    hfill[t] = 0;
    __syncthreads();
    for (int i = t; i < cnt; i += 256)
        atomicAdd(&hcnt[((unsigned)tmp[(size_t)base + i].x) >> IDX_BITS], 1);
    __syncthreads();
    sh[t] = hcnt[t];
    __syncthreads();
    for (int off = 1; off < 256; off <<= 1) {
        int x = (t >= off) ? sh[t - off] : 0;
        __syncthreads();
        sh[t] += x;
        __syncthreads();
    }
    hoff[t] = sh[t] - hcnt[t];
    if (nodeBase + t < n) offs[offsBase + t] = base + hoff[t];
    __syncthreads();
    for (int i = t; i < cnt; i += 256) {
        int2 v = tmp[(size_t)base + i];
        unsigned loc = ((unsigned)v.x) >> IDX_BITS;
        int p = atomicAdd(&hfill[loc], 1);
        unsigned idx16 = ((unsigned)v.x & IDX_MASK) & 0xffffu;
        unsigned wbits = (unsigned)(unsigned short)f2bf(__int_as_float(v.y));
        ew[(size_t)base + hoff[loc] + p] = (wbits << 16) | idx16;
    }
}

// ===================== aggregation: 4 nodes/wave, one branch per launch ========
// ew entry: (bf16 w << 16) | idx16. One shfl broadcasts both.
__global__ __launch_bounds__(256) void k_agg(const unsigned* __restrict__ ew,
                                             const int* __restrict__ offs,
                                             const __hip_bfloat16* __restrict__ fb,
                                             const float* __restrict__ bias,
                                             float* __restrict__ out, int n,
                                             int offsBase, int outoff, int norm) {
    int wave = (int)(((long long)blockIdx.x * blockDim.x + threadIdx.x) >> 6);
    int lane = threadIdx.x & 63;
    int nq = (n + 3) >> 2;
    if (wave >= nq) return;
    int q = lane >> 4;        // quarter 0..3 (node within group)
    int fg = lane & 15;       // feature group (4 feats, uint2)
    int qb = q << 4;          // quarter base lane

    int node = wave * 4 + q;
    bool nodeValid = node < n;
    int wid = offsBase + (nodeValid ? node : 0);
    int start = offs[wid];
    int deg = nodeValid ? offs[wid + 1] - start : 0;

    const uint2* fbase = (const uint2*)fb;   // row = 16 uint2
    float acc[4] = {0.f, 0.f, 0.f, 0.f};
    float sw = 0.f;

    for (int c0 = 0; c0 < deg; c0 += 16) {
        int cnt = min(16, deg - c0);
        bool valid = fg < cnt;
        unsigned e = valid ? ew[(size_t)start + c0 + fg] : 0u;
        float w = bfhi(e);                   // 0.0f when invalid
        float ts = w;
        ts += __shfl_xor(ts, 1);  ts += __shfl_xor(ts, 2);
        ts += __shfl_xor(ts, 4);  ts += __shfl_xor(ts, 8);
        sw += ts;
#pragma unroll 4
        for (int k = 0; k < cnt; ++k) {
            unsigned ek = (unsigned)__shfl((int)e, qb + k);
            float wk = bfhi(ek);
            int ik = (int)(ek & 0xffffu);
            uint2 pv = fbase[(size_t)ik * 16 + fg];
            acc[0] += wk * bflo(pv.x); acc[1] += wk * bfhi(pv.x);
            acc[2] += wk * bflo(pv.y); acc[3] += wk * bfhi(pv.y);
        }
    }
    if (nodeValid) {
        float inv = norm ? (deg > 0 ? __builtin_amdgcn_rcpf(sw) : 0.f) : 1.f;
        float4 bb = *(const float4*)(bias + fg * 4);
        float z0 = acc[0] * inv + bb.x;
        float z1 = acc[1] * inv + bb.y;
        float z2 = acc[2] * inv + bb.z;
        float z3 = acc[3] * inv + bb.w;
        z0 = z0 > 0.f ? z0 : __expf(z0) - 1.f;
        z1 = z1 > 0.f ? z1 : __expf(z1) - 1.f;
        z2 = z2 > 0.f ? z2 : __expf(z2) - 1.f;
        z3 = z3 > 0.f ? z3 : __expf(z3) - 1.f;
        *(float4*)(out + (size_t)node * 128 + outoff + fg * 4) = make_float4(z0, z1, z2, z3);
    }
}

// ===================== launch =====================
extern "C" void kernel_launch(void* const* d_in, const int* in_sizes, int n_in,
                              void* d_out, int out_size, void* d_ws, size_t ws_size,
                              hipStream_t stream) {
    const float* h        = (const float*)d_in[0];
    const int*   src0     = (const int*)d_in[1];
    const int*   dst0     = (const int*)d_in[2];
    const int*   row2     = (const int*)d_in[3];
    const int*   col2     = (const int*)d_in[4];
    const float* adj_val  = (const float*)d_in[5];
    const float* Wg       = (const float*)d_in[6];
    const float* attn_l   = (const float*)d_in[7];
    const float* attn_r   = (const float*)d_in[8];
    const float* bias_gat = (const float*)d_in[9];
    const float* Wc       = (const float*)d_in[10];
    const float* bias_gc  = (const float*)d_in[11];

    int n  = in_sizes[0] / IN_F;
    int E_ = in_sizes[1];
    float* out = (float*)d_out;

    int NB = (n + BKT_MASK) >> BKT_SH;
    int TB = 2 * NB;
    if (TB > MAXTB) return;
    if (n > 65536) return;                 // ew idx fits in 16 bits
    if (E_ >= (1 << IDX_BITS)) return;

    int nchunk = (E_ + CHUNK - 1) / CHUNK;

    // ---- workspace layout (ew aliases chunkhist: chunkhist dead after k_part) ----
    char* p = (char*)d_ws;
    auto alloc = [&](size_t bytes, size_t align) -> void* {
        size_t a = ((size_t)p + align - 1) & ~(align - 1);
        p = (char*)(a + bytes);
        return (void*)a;
    };
    size_t Rbytes = 2 * (size_t)E_ * sizeof(int2);                 // >= chunkhist, >= ew(4B)
    if ((size_t)nchunk * TB * sizeof(int) > Rbytes) return;
    char* R = (char*)alloc(Rbytes, 256);
    int*      chunkhist = (int*)R;
    unsigned* ew        = (unsigned*)R;
    int2*  tmp   = (int2*) alloc(2 * (size_t)E_ * sizeof(int2), 256);
    int*   offs  = (int*)  alloc((2 * (size_t)n + 1) * sizeof(int), 16);
    float* el    = (float*)alloc((size_t)n * sizeof(float), 16);
    float* er    = (float*)alloc((size_t)n * sizeof(float), 16);
    int*   bcnt  = (int*)  alloc(2 * (size_t)TB * PAD * sizeof(int), 64);  // + gfill
    int*   gfill = bcnt + TB * PAD;
    int*   boffs = (int*)  alloc(((size_t)TB + 1) * sizeof(int), 16);
    __hip_bfloat16* feat    = (__hip_bfloat16*)alloc((size_t)n * OUT_F * sizeof(__hip_bfloat16), 256);
    __hip_bfloat16* support = (__hip_bfloat16*)alloc((size_t)n * OUT_F * sizeof(__hip_bfloat16), 256);
    size_t need = (size_t)(p - (char*)d_ws);
    if (ws_size < need) return;

    int G1 = (n + 63) / 64;

    hipMemsetAsync(bcnt, 0, 2 * (size_t)TB * PAD * sizeof(int), stream);
    k_fused<<<G1 + nchunk, 256, 0, stream>>>(h, Wg, Wc, attn_l, attn_r,
                                             feat, support, el, er, n, G1,
                                             dst0, row2, bcnt, chunkhist, NB, E_);
    k_part<<<nchunk, 256, 0, stream>>>(src0, dst0, row2, col2, adj_val,
                                       el, er, bcnt, chunkhist, gfill,
                                       boffs, offs, 2 * n, tmp, NB, E_, 2 * E_);
    k_bbuild<<<TB, 256, 0, stream>>>(tmp, boffs, offs, ew, NB, n);
    int nq = (n + 3) >> 2;
    int aggblocks = (int)(((long long)nq * 64 + 255) / 256);
    // GAT branch (normalized), then GC branch
    k_agg<<<aggblocks, 256, 0, stream>>>(ew, offs, feat, bias_gat, out, n,
                                         0, 0, 1);
    k_agg<<<aggblocks, 256, 0, stream>>>(ew, offs, support, bias_gc, out, n,
                                         n, OUT_F, 0);
}

// Round 16
// 116.660 us; speedup vs baseline: 1.0744x; 1.0744x over previous
//
#include <hip/hip_runtime.h>
#include <hip/hip_bf16.h>
#include <math.h>

#define IN_F 128
#define OUT_F 64
#define BKT_SH 8          // 256 nodes per bucket
#define BKT_MASK 255
#define CHUNK 4096        // edges per partition block (196 blocks at E=800k)
#define MAXTB 800         // max total buckets (2 * ceil(n/256)); n<=102k
#define IDX_BITS 24       // packed tmp: (local<<24)|idx ; needs n,E < 2^24
#define IDX_MASK ((1u << IDX_BITS) - 1u)
#define PAD 16            // bcnt/gfill padding: one counter per 64B line

typedef __attribute__((ext_vector_type(8))) short bf16x8;
typedef __attribute__((ext_vector_type(4))) float f32x4;

__device__ inline short f2bf(float x) {
    __hip_bfloat16 b = __float2bfloat16(x);
    return *reinterpret_cast<short*>(&b);
}
__device__ inline float bflo(unsigned u) { return __uint_as_float(u << 16); }
__device__ inline float bfhi(unsigned u) { return __uint_as_float(u & 0xffff0000u); }

// ===================== fused: MFMA dual GEMM + bucket count =====================
__global__ __launch_bounds__(256) void k_fused(const float* __restrict__ h,
                                               const float* __restrict__ Wg,
                                               const float* __restrict__ Wc,
                                               const float* __restrict__ attn_l,
                                               const float* __restrict__ attn_r,
                                               __hip_bfloat16* __restrict__ feat,
                                               __hip_bfloat16* __restrict__ support,
                                               float* __restrict__ el,
                                               float* __restrict__ er, int n, int G1,
                                               const int* __restrict__ dst0,
                                               const int* __restrict__ row2,
                                               int* __restrict__ bcnt,
                                               int* __restrict__ chunkhist,
                                               int NB, int E_) {
    __shared__ short Wl[16][128][8];   // 32 KB
    __shared__ int hist[MAXTB];        // 3.2 KB

    if ((int)blockIdx.x >= G1) {
        // ---------- count part ----------
        int TB = 2 * NB;
        int t = threadIdx.x;
        int chunk = (int)blockIdx.x - G1;
        for (int i = t; i < TB; i += 256) hist[i] = 0;
        __syncthreads();
        int e0 = chunk * CHUNK;
        for (int i = t; i < CHUNK; i += 256) {
            int e = e0 + i;
            if (e < E_) {
                atomicAdd(&hist[dst0[e] >> BKT_SH], 1);
                atomicAdd(&hist[NB + (row2[e] >> BKT_SH)], 1);
            }
        }
        __syncthreads();
        int* hrow = chunkhist + (size_t)chunk * TB;
        for (int b = t; b < TB; b += 256) {
            int c = hist[b];
            hrow[b] = c;
            if (c) atomicAdd(&bcnt[b * PAD], c);   // padded: 1 counter / line
        }
        return;
    }

    // ---------- GEMM part ----------
    for (int i = threadIdx.x; i < 128 * 32; i += 256) {
        int k = i >> 5;
        int c4 = (i & 31) << 2;
        float4 v4 = (c4 < 64) ? *(const float4*)(Wg + k * 64 + c4)
                              : *(const float4*)(Wc + k * 64 + (c4 - 64));
        short* dst = &Wl[k >> 3][c4][k & 7];
        dst[0]  = f2bf(v4.x);
        dst[8]  = f2bf(v4.y);
        dst[16] = f2bf(v4.z);
        dst[24] = f2bf(v4.w);
    }
    __syncthreads();

    int lane = threadIdx.x & 63;
    int wv = threadIdx.x >> 6;
    int li = lane & 15, lg = lane >> 4;
    int row0 = blockIdx.x * 64 + wv * 16;

    f32x4 acc[8];
#pragma unroll
    for (int ct = 0; ct < 8; ++ct) acc[ct] = (f32x4){0.f, 0.f, 0.f, 0.f};

    int ar = row0 + li;
    if (ar >= n) ar = n - 1;
    const float* hrow = h + (size_t)ar * IN_F + lg * 8;
#pragma unroll
    for (int q = 0; q < 4; ++q) {
        float4 a0 = *(const float4*)(hrow + q * 32);
        float4 a1 = *(const float4*)(hrow + q * 32 + 4);
        bf16x8 af;
        af[0] = f2bf(a0.x); af[1] = f2bf(a0.y); af[2] = f2bf(a0.z); af[3] = f2bf(a0.w);
        af[4] = f2bf(a1.x); af[5] = f2bf(a1.y); af[6] = f2bf(a1.z); af[7] = f2bf(a1.w);
        int kg = q * 4 + lg;
#pragma unroll
        for (int ct = 0; ct < 8; ++ct) {
            bf16x8 bfr = *(const bf16x8*)&Wl[kg][ct * 16 + li][0];
            acc[ct] = __builtin_amdgcn_mfma_f32_16x16x32_bf16(af, bfr, acc[ct], 0, 0, 0);
        }
    }

    float alv[4], arv[4];
#pragma unroll
    for (int ct = 0; ct < 4; ++ct) {
        alv[ct] = attn_l[ct * 16 + li];
        arv[ct] = attn_r[ct * 16 + li];
    }
#pragma unroll
    for (int r = 0; r < 4; ++r) {
        int row = row0 + lg * 4 + r;
        float pl = 0.f, pr = 0.f;
#pragma unroll
        for (int ct = 0; ct < 4; ++ct) {
            pl += acc[ct][r] * alv[ct];
            pr += acc[ct][r] * arv[ct];
        }
#pragma unroll
        for (int m = 8; m; m >>= 1) {
            pl += __shfl_xor(pl, m);
            pr += __shfl_xor(pr, m);
        }
        if (li == 0 && row < n) { el[row] = pl; er[row] = pr; }
    }

#pragma unroll
    for (int r = 0; r < 4; ++r) {
        int row = row0 + lg * 4 + r;
        if (row >= n) continue;
#pragma unroll
        for (int ct = 0; ct < 4; ++ct)
            feat[(size_t)row * OUT_F + ct * 16 + li] = __float2bfloat16(acc[ct][r]);
#pragma unroll
        for (int ct = 4; ct < 8; ++ct)
            support[(size_t)row * OUT_F + (ct - 4) * 16 + li] = __float2bfloat16(acc[ct][r]);
    }
}

// ===================== partition: 1024 threads/block ==========================
// Same 196 chunks (run lengths preserved -> coalesced scatter), 4x the waves.
// Per-block scan of bcnt (1 entry/thread, TB < 1024); block 0 publishes boffs.
__global__ __launch_bounds__(1024) void k_part(const int* __restrict__ src0,
                                               const int* __restrict__ dst0,
                                               const int* __restrict__ row2,
                                               const int* __restrict__ col2,
                                               const float* __restrict__ adj_val,
                                               const float* __restrict__ el,
                                               const float* __restrict__ er,
                                               const int* __restrict__ bcnt,
                                               const int* __restrict__ chunkhist,
                                               int* __restrict__ gfill,
                                               int* __restrict__ boffs,
                                               int* __restrict__ offs, int tot,
                                               int2* __restrict__ tmp,
                                               int NB, int E_, int grand) {
    __shared__ int bo[MAXTB + 1];      // local boffs
    __shared__ int hist[MAXTB];
    __shared__ int rbase[MAXTB];
    __shared__ int sh[1024];
    int TB = 2 * NB;
    int t = threadIdx.x;

    // ---- block-local exclusive scan of bcnt (1 entry per thread) ----
    {
        int v = (t < TB) ? bcnt[t * PAD] : 0;
        sh[t] = v;
        __syncthreads();
        for (int off = 1; off < 1024; off <<= 1) {
            int x = (t >= off) ? sh[t - off] : 0;
            __syncthreads();
            sh[t] += x;
            __syncthreads();
        }
        if (t < TB) bo[t] = sh[t] - v;
        if (t == 0) bo[TB] = grand;
    }
    __syncthreads();

    if (blockIdx.x == 0) {
        for (int b = t; b <= TB; b += 1024) boffs[b] = bo[b];
        if (t == 0) offs[tot] = grand;
    }

    const int* hrow = chunkhist + (size_t)blockIdx.x * TB;
    for (int b = t; b < TB; b += 1024) {
        int c = hrow[b];
        int bb = 0;
        if (c) bb = bo[b] + atomicAdd(&gfill[b * PAD], c);
        rbase[b] = bb;
        hist[b] = 0;   // local fill counters
    }
    __syncthreads();
    int e0 = blockIdx.x * CHUNK;
    for (int i = t; i < CHUNK; i += 1024) {
        int e = e0 + i;
        if (e < E_) {
            int s = src0[e];
            int d = dst0[e];
            int b = d >> BKT_SH;
            int p = atomicAdd(&hist[b], 1);
            float w = el[s] + er[d];
            w = w > 0.f ? w : 0.2f * w;
            w = __expf(w);                       // no-max softmax
            tmp[(size_t)rbase[b] + p] =
                make_int2((int)(((unsigned)(d & BKT_MASK) << IDX_BITS) | (unsigned)s),
                          __float_as_int(w));
            int r = row2[e];
            int b2 = NB + (r >> BKT_SH);
            int p2 = atomicAdd(&hist[b2], 1);
            tmp[(size_t)rbase[b2] + p2] =
                make_int2((int)(((unsigned)(r & BKT_MASK) << IDX_BITS) | (unsigned)col2[e]),
                          __float_as_int(adj_val[e]));
        }
    }
}

// ===================== build fine CSR (gather-free permute) ==========
// Packs ew entries to 4 bytes: (bf16(w) << 16) | node_idx (n < 65536).
__global__ __launch_bounds__(256) void k_bbuild(const int2* __restrict__ tmp,
                                                const int* __restrict__ boffs,
                                                int* __restrict__ offs,
                                                unsigned* __restrict__ ew, int NB, int n) {
    __shared__ int hcnt[256], hoff[256], hfill[256], sh[256];
    int b = blockIdx.x;
    int t = threadIdx.x;
    int base = boffs[b];
    int cnt = boffs[b + 1] - base;
    bool isGat = b < NB;
    int nodeBase = (isGat ? b : b - NB) << BKT_SH;
    int offsBase = (isGat ? 0 : n) + nodeBase;

    hcnt[t] = 0;
    hfill[t] = 0;
    __syncthreads();
    for (int i = t; i < cnt; i += 256)
        atomicAdd(&hcnt[((unsigned)tmp[(size_t)base + i].x) >> IDX_BITS], 1);
    __syncthreads();
    sh[t] = hcnt[t];
    __syncthreads();
    for (int off = 1; off < 256; off <<= 1) {
        int x = (t >= off) ? sh[t - off] : 0;
        __syncthreads();
        sh[t] += x;
        __syncthreads();
    }
    hoff[t] = sh[t] - hcnt[t];
    if (nodeBase + t < n) offs[offsBase + t] = base + hoff[t];
    __syncthreads();
    for (int i = t; i < cnt; i += 256) {
        int2 v = tmp[(size_t)base + i];
        unsigned loc = ((unsigned)v.x) >> IDX_BITS;
        int p = atomicAdd(&hfill[loc], 1);
        unsigned idx16 = ((unsigned)v.x & IDX_MASK) & 0xffffu;
        unsigned wbits = (unsigned)(unsigned short)f2bf(__int_as_float(v.y));
        ew[(size_t)base + hoff[loc] + p] = (wbits << 16) | idx16;
    }
}

// ===================== aggregation: 4 nodes per wave, both branches ============
// ew entry: (bf16 w << 16) | idx16. One shfl broadcasts both.
// Waves [0, nq): GAT; waves [nq, 2nq): GC. nq = ceil(n/4).
__global__ __launch_bounds__(256) void k_agg(const unsigned* __restrict__ ew,
                                             const int* __restrict__ offs,
                                             const __hip_bfloat16* __restrict__ feat,
                                             const __hip_bfloat16* __restrict__ support,
                                             const float* __restrict__ bias_gat,
                                             const float* __restrict__ bias_gc,
                                             float* __restrict__ out, int n) {
    int wave = (int)(((long long)blockIdx.x * blockDim.x + threadIdx.x) >> 6);
    int lane = threadIdx.x & 63;
    int nq = (n + 3) >> 2;
    if (wave >= 2 * nq) return;
    int q = lane >> 4;        // quarter 0..3 (node within group)
    int fg = lane & 15;       // feature group (4 feats, uint2)
    int qb = q << 4;          // quarter base lane

    bool isGat = wave < nq;
    int node = (isGat ? wave : wave - nq) * 4 + q;
    bool nodeValid = node < n;
    int wid = (isGat ? 0 : n) + (nodeValid ? node : 0);
    int start = offs[wid];
    int deg = nodeValid ? offs[wid + 1] - start : 0;

    const uint2* fbase = (const uint2*)(isGat ? feat : support);  // row = 16 uint2
    float acc[4] = {0.f, 0.f, 0.f, 0.f};
    float sw = 0.f;

    for (int c0 = 0; c0 < deg; c0 += 16) {
        int cnt = min(16, deg - c0);
        bool valid = fg < cnt;
        unsigned e = valid ? ew[(size_t)start + c0 + fg] : 0u;
        float w = bfhi(e);                   // 0.0f when invalid
        float ts = w;
        ts += __shfl_xor(ts, 1);  ts += __shfl_xor(ts, 2);
        ts += __shfl_xor(ts, 4);  ts += __shfl_xor(ts, 8);
        sw += ts;
#pragma unroll 4
        for (int k = 0; k < cnt; ++k) {
            unsigned ek = (unsigned)__shfl((int)e, qb + k);
            float wk = bfhi(ek);
            int ik = (int)(ek & 0xffffu);
            uint2 pv = fbase[(size_t)ik * 16 + fg];
            acc[0] += wk * bflo(pv.x); acc[1] += wk * bfhi(pv.x);
            acc[2] += wk * bflo(pv.y); acc[3] += wk * bfhi(pv.y);
        }
    }
    if (nodeValid) {
        float inv = isGat ? (deg > 0 ? __builtin_amdgcn_rcpf(sw) : 0.f) : 1.f;
        const float* bias = isGat ? bias_gat : bias_gc;
        int outoff = isGat ? 0 : OUT_F;
        float4 bb = *(const float4*)(bias + fg * 4);
        float z0 = acc[0] * inv + bb.x;
        float z1 = acc[1] * inv + bb.y;
        float z2 = acc[2] * inv + bb.z;
        float z3 = acc[3] * inv + bb.w;
        z0 = z0 > 0.f ? z0 : __expf(z0) - 1.f;
        z1 = z1 > 0.f ? z1 : __expf(z1) - 1.f;
        z2 = z2 > 0.f ? z2 : __expf(z2) - 1.f;
        z3 = z3 > 0.f ? z3 : __expf(z3) - 1.f;
        *(float4*)(out + (size_t)node * 128 + outoff + fg * 4) = make_float4(z0, z1, z2, z3);
    }
}

// ===================== launch =====================
extern "C" void kernel_launch(void* const* d_in, const int* in_sizes, int n_in,
                              void* d_out, int out_size, void* d_ws, size_t ws_size,
                              hipStream_t stream) {
    const float* h        = (const float*)d_in[0];
    const int*   src0     = (const int*)d_in[1];
    const int*   dst0     = (const int*)d_in[2];
    const int*   row2     = (const int*)d_in[3];
    const int*   col2     = (const int*)d_in[4];
    const float* adj_val  = (const float*)d_in[5];
    const float* Wg       = (const float*)d_in[6];
    const float* attn_l   = (const float*)d_in[7];
    const float* attn_r   = (const float*)d_in[8];
    const float* bias_gat = (const float*)d_in[9];
    const float* Wc       = (const float*)d_in[10];
    const float* bias_gc  = (const float*)d_in[11];

    int n  = in_sizes[0] / IN_F;
    int E_ = in_sizes[1];
    float* out = (float*)d_out;

    int NB = (n + BKT_MASK) >> BKT_SH;
    int TB = 2 * NB;
    if (TB > MAXTB) return;
    if (n > 65536) return;                 // ew idx fits in 16 bits
    if (E_ >= (1 << IDX_BITS)) return;

    int nchunk = (E_ + CHUNK - 1) / CHUNK;

    // ---- workspace layout (ew aliases chunkhist: chunkhist dead after k_part) ----
    char* p = (char*)d_ws;
    auto alloc = [&](size_t bytes, size_t align) -> void* {
        size_t a = ((size_t)p + align - 1) & ~(align - 1);
        p = (char*)(a + bytes);
        return (void*)a;
    };
    size_t Rbytes = 2 * (size_t)E_ * sizeof(int2);                 // >= chunkhist, >= ew(4B)
    if ((size_t)nchunk * TB * sizeof(int) > Rbytes) return;
    char* R = (char*)alloc(Rbytes, 256);
    int*      chunkhist = (int*)R;
    unsigned* ew        = (unsigned*)R;
    int2*  tmp   = (int2*) alloc(2 * (size_t)E_ * sizeof(int2), 256);
    int*   offs  = (int*)  alloc((2 * (size_t)n + 1) * sizeof(int), 16);
    float* el    = (float*)alloc((size_t)n * sizeof(float), 16);
    float* er    = (float*)alloc((size_t)n * sizeof(float), 16);
    int*   bcnt  = (int*)  alloc(2 * (size_t)TB * PAD * sizeof(int), 64);  // + gfill
    int*   gfill = bcnt + TB * PAD;
    int*   boffs = (int*)  alloc(((size_t)TB + 1) * sizeof(int), 16);
    __hip_bfloat16* feat    = (__hip_bfloat16*)alloc((size_t)n * OUT_F * sizeof(__hip_bfloat16), 256);
    __hip_bfloat16* support = (__hip_bfloat16*)alloc((size_t)n * OUT_F * sizeof(__hip_bfloat16), 256);
    size_t need = (size_t)(p - (char*)d_ws);
    if (ws_size < need) return;

    int G1 = (n + 63) / 64;

    hipMemsetAsync(bcnt, 0, 2 * (size_t)TB * PAD * sizeof(int), stream);
    k_fused<<<G1 + nchunk, 256, 0, stream>>>(h, Wg, Wc, attn_l, attn_r,
                                             feat, support, el, er, n, G1,
                                             dst0, row2, bcnt, chunkhist, NB, E_);
    k_part<<<nchunk, 1024, 0, stream>>>(src0, dst0, row2, col2, adj_val,
                                        el, er, bcnt, chunkhist, gfill,
                                        boffs, offs, 2 * n, tmp, NB, E_, 2 * E_);
    k_bbuild<<<TB, 256, 0, stream>>>(tmp, boffs, offs, ew, NB, n);
    int nq = (n + 3) >> 2;
    long long aggthreads = 2LL * nq * 64;
    k_agg<<<(int)((aggthreads + 255) / 256), 256, 0, stream>>>(
        ew, offs, feat, support, bias_gat, bias_gc, out, n);
}